// Round 4
// baseline (880.071 us; speedup 1.0000x reference)
//
#include <hip/hip_runtime.h>

// Problem constants (B=8, S=2048, D=1024, H=4096, E=8, CAP_FACTOR=1.5)
#define NTOK 16384
#define DDIM 1024
#define EEXP 8
#define HDIM 4096
#define CAP  3072               // int(1.5 * 16384 / 8)
#define ECAP (EEXP*CAP)         // 24576

// Workspace layout (bytes)
#define OFF_GATE 0u                          // float[NTOK]
#define OFF_GIDX 65536u                      // int[NTOK]
#define OFF_SLOT 131072u                     // int[NTOK]
#define OFF_TOS  196608u                     // int[ECAP]
#define OFF_CNT  294912u                     // int[8]
#define OFF_PIMP 294976u                     // float[4096*8]
#define OFF_PFX  430080u                     // int[9] compact-tile prefix
#define OFF_XBF  1048576u                    // ushort[NTOK*DDIM]       (32 MB)
#define OFF_W1T  34603008u                   // ushort[E*HDIM*DDIM]     (64 MB) [e][n][k]
#define OFF_W2T  101711872u                  // ushort[E*DDIM*HDIM]     (64 MB) [e][n][k]
#define OFF_HB   168820736u                  // ushort[ECAP*HDIM]       (192 MB)
#define WS_NEED  370147328u

typedef float f32x4  __attribute__((ext_vector_type(4)));
typedef short bf16x8 __attribute__((ext_vector_type(8)));
typedef unsigned short u16x8 __attribute__((ext_vector_type(8)));

__device__ __forceinline__ unsigned short f2bf(float f){
  unsigned int u = __float_as_uint(f);
  unsigned int r = (u + 0x7fffu + ((u >> 16) & 1u)) >> 16;   // RNE
  return (unsigned short)r;
}
__device__ __forceinline__ float siluf(float v){ return v/(1.0f+__expf(-v)); }

// async global->LDS, 16B per lane; LDS dst must be wave-uniform base (+lane*16 implicit)
__device__ __forceinline__ void gl16(const void* g, void* l){
  __builtin_amdgcn_global_load_lds((const __attribute__((address_space(1))) unsigned int*)g,
                                   (__attribute__((address_space(3))) unsigned int*)l,
                                   16, 0, 0);
}

// ---------------------------------------------------------------------------
// Router: one wave per token. Also emits x in bf16 (fused conversion).
// ---------------------------------------------------------------------------
__global__ __launch_bounds__(256) void router_kernel(
    const float* __restrict__ x, const float* __restrict__ Wr,
    const float* __restrict__ br, float* __restrict__ gate_value,
    int* __restrict__ gate_idx, float* __restrict__ partial_imp,
    unsigned short* __restrict__ xbf)
{
  __shared__ float pbuf[4][8];
  const int wave = threadIdx.x >> 6;
  const int lane = threadIdx.x & 63;
  const int n = blockIdx.x*4 + wave;
  float acc[8];
#pragma unroll
  for (int e=0;e<8;e++) acc[e]=0.0f;
  const float* xr = x + (size_t)n*DDIM;
  unsigned short* xbr = xbf + (size_t)n*DDIM;
#pragma unroll
  for (int k=0;k<16;k++){
    const int d = k*64 + lane;
    const float xv = xr[d];
    xbr[d] = f2bf(xv);
    const float4 w0 = ((const float4*)(Wr + (size_t)d*8))[0];
    const float4 w1 = ((const float4*)(Wr + (size_t)d*8))[1];
    acc[0] += xv*w0.x; acc[1] += xv*w0.y; acc[2] += xv*w0.z; acc[3] += xv*w0.w;
    acc[4] += xv*w1.x; acc[5] += xv*w1.y; acc[6] += xv*w1.z; acc[7] += xv*w1.w;
  }
#pragma unroll
  for (int e=0;e<8;e++){
    acc[e] += __shfl_xor(acc[e], 32, 64);
    acc[e] += __shfl_xor(acc[e], 16, 64);
    acc[e] += __shfl_xor(acc[e],  8, 64);
    acc[e] += __shfl_xor(acc[e],  4, 64);
    acc[e] += __shfl_xor(acc[e],  2, 64);
    acc[e] += __shfl_xor(acc[e],  1, 64);
  }
  if (lane==0){
    float lg[8];
    float mx = -3.4e38f;
    int bi = 0;
#pragma unroll
    for (int e=0;e<8;e++) lg[e] = acc[e] + br[e];
#pragma unroll
    for (int e=0;e<8;e++){ if (lg[e] > mx){ mx = lg[e]; bi = e; } }
    float s = 0.f;
#pragma unroll
    for (int e=0;e<8;e++){ lg[e] = __expf(lg[e]-mx); s += lg[e]; }
    const float inv = 1.0f/s;
    gate_value[n] = inv;
    gate_idx[n] = bi;
#pragma unroll
    for (int e=0;e<8;e++) pbuf[wave][e] = lg[e]*inv;
  }
  __syncthreads();
  if (threadIdx.x < 8){
    partial_imp[(size_t)blockIdx.x*8 + threadIdx.x] =
      pbuf[0][threadIdx.x]+pbuf[1][threadIdx.x]+pbuf[2][threadIdx.x]+pbuf[3][threadIdx.x];
  }
}

// ---------------------------------------------------------------------------
// Scan: FIFO positions per expert (single block) + aux losses + compact-tile
// prefix pfx[9] (256-row tiles per expert) for balanced ffn grids.
// ---------------------------------------------------------------------------
__global__ __launch_bounds__(256) void scan_kernel(
    const int* __restrict__ gate_idx, const float* __restrict__ partial_imp,
    int* __restrict__ slot_or_neg, int* __restrict__ tok_of_slot,
    int* __restrict__ cnt, int* __restrict__ pfx, float* __restrict__ out_losses)
{
  __shared__ int hist[256][8];
  __shared__ float impbuf[32][8];
  const int t = threadIdx.x;
  int h[8];
#pragma unroll
  for (int e=0;e<8;e++) h[e]=0;
  const int base = t*64;
  for (int i=0;i<64;i++) h[gate_idx[base+i]]++;
#pragma unroll
  for (int e=0;e<8;e++) hist[t][e]=h[e];
  {
    const int e = t & 7, c = t >> 3;
    float s = 0.f;
    for (int r=c; r<4096; r+=32) s += partial_imp[(size_t)r*8+e];
    impbuf[c][e] = s;
  }
  __syncthreads();
  if (t < 8){
    int run = 0;
    for (int i=0;i<256;i++){ int v = hist[i][t]; hist[i][t] = run; run += v; }
    cnt[t] = run < CAP ? run : CAP;
  }
  __syncthreads();
#pragma unroll
  for (int e=0;e<8;e++) h[e]=hist[t][e];
  for (int i=0;i<64;i++){
    const int n = base+i;
    const int e = gate_idx[n];
    const int p = h[e]++;
    if (p < CAP){ const int s = e*CAP+p; slot_or_neg[n]=s; tok_of_slot[s]=n; }
    else slot_or_neg[n] = -1;
  }
  if (t==0){
    float imp[8]; float m = 0.f;
    for (int e=0;e<8;e++){ float s=0.f; for (int c=0;c<32;c++) s+=impbuf[c][e]; imp[e]=s; m+=s; }
    m *= 0.125f;
    float var = 0.f;
    for (int e=0;e<8;e++){ const float d=imp[e]-m; var += d*d; }
    var *= 0.125f;
    out_losses[0] = 1.0f;
    out_losses[1] = var/(m*m);
    // compact active-tile prefix (256-row tiles)
    int run = 0;
    pfx[0] = 0;
    for (int e=0;e<8;e++){ run += (cnt[e] + 255) >> 8; pfx[e+1] = run; }
  }
}

// ---------------------------------------------------------------------------
// Weight transpose + fp32->bf16, both W1 and W2 in one launch.
// W [E][K][N] -> Wt [E][N][K] (k-contiguous rows for the MFMA B-operand).
// ---------------------------------------------------------------------------
__global__ __launch_bounds__(256) void cvt_w_t(
    const float* __restrict__ W1, const float* __restrict__ W2,
    unsigned short* __restrict__ W1t, unsigned short* __restrict__ W2t)
{
  __shared__ float t[64][65];
  const bool second = blockIdx.z >= 8;
  const int e = second ? (int)blockIdx.z - 8 : (int)blockIdx.z;
  const float* W = second ? W2 : W1;
  unsigned short* Wt = second ? W2t : W1t;
  const int K = second ? HDIM : DDIM;
  const int N = second ? DDIM : HDIM;
  const int nt = second ? (int)blockIdx.y : (int)blockIdx.x;
  const int kt = second ? (int)blockIdx.x : (int)blockIdx.y;
  const int n0 = nt*64, k0 = kt*64;

  const int lr = threadIdx.x >> 4;          // 0..15
  const int lc = (threadIdx.x & 15) * 4;    // 0..60
#pragma unroll
  for (int i=0;i<4;i++){
    const int r = i*16 + lr;
    const float4 v = *(const float4*)(W + ((size_t)e*K + k0 + r)*N + n0 + lc);
    t[r][lc+0]=v.x; t[r][lc+1]=v.y; t[r][lc+2]=v.z; t[r][lc+3]=v.w;
  }
  __syncthreads();
  const int sr = threadIdx.x >> 3;          // 0..31 (n-row within half)
  const int sc = (threadIdx.x & 7) * 8;     // 0..56 (k offset)
#pragma unroll
  for (int i=0;i<2;i++){
    const int r = i*32 + sr;
    u16x8 o;
#pragma unroll
    for (int j=0;j<8;j++) o[j] = f2bf(t[sc+j][r]);
    *(u16x8*)(Wt + ((size_t)e*N + n0 + r)*K + k0 + sc) = o;
  }
}

// ---------------------------------------------------------------------------
// 8-phase 256x256 grouped FFN GEMM (T3+T4+T5). BK=64 as two 32-k halves;
// 8 waves (2M x 4N), per-wave 128x64 = acc[8][4] of 16x16x32 bf16 MFMA.
//
// COMPACT GRID (round-4): scan emits pfx[] of active 256-row tiles per
// expert. bid -> (ct, coltile) with coltile fastest; ct >= pfx[8] exits.
// Active work is a contiguous bid range -> uniform CU residency (round-3's
// loss was dispatch holes: Occupancy 13% with a working per-CU schedule).
//
// LDS ring: per operand 4 half-slots (16 KB): slot(t,kh)=(2t+kh)&3.
// Half-slot: [256 rows][32 k] bf16, 16B chunks XOR-swizzled
// chunk' = chunk ^ ((row>>1)&3); gl16 writes linearly so the swizzle is
// pre-applied to the per-lane GLOBAL source k-chunk (both-sides rule).
// Per K-tile 4 phases: {ds_read subtile | issue 1 half-tile prefetch ->
// counted vmcnt(4) at phases 1,3 -> s_barrier -> lgkmcnt(0) -> setprio(1),
// 16 MFMA, setprio(0) -> s_barrier}; vmcnt never 0 in the main loop.
// ---------------------------------------------------------------------------
template<int PHASE>
__global__ __launch_bounds__(512,2) void ffn_mfma(
    const unsigned short* __restrict__ A,   // PHASE1: xbf [NTOK][1024]; PHASE2: hbf [ECAP][4096]
    const unsigned short* __restrict__ Bt,  // [E][NN][K] k-contiguous
    const float* __restrict__ bias,         // [E][NN]
    const int* __restrict__ tok_of_slot,
    const int* __restrict__ cnt,
    const int* __restrict__ pfx,
    const float* __restrict__ gate_value,
    void* __restrict__ Out)
{
  constexpr int K  = (PHASE==1)? DDIM : HDIM;
  constexpr int NN = (PHASE==1)? HDIM : DDIM;
  constexpr int NCT = NN/256;               // 16 or 4 coltiles
  constexpr int NT = K/64;                  // K-tiles: 16 or 64 (even)

  // ---- compact work mapping
  int p[9];
#pragma unroll
  for (int i=0;i<9;i++) p[i] = pfx[i];
  const int bid = blockIdx.x;
  const int ct = bid / NCT;
  const int coltile = bid - ct*NCT;
  if (ct >= p[8]) return;                   // beyond active tiles
  int e = 0;
#pragma unroll
  for (int i=1;i<8;i++) e += (ct >= p[i]);
  const int r0 = (ct - p[e])*256;
  const int ce = cnt[e];
  const int slotbase = e*CAP + r0;

  __shared__ alignas(16) char smem[131072]; // A: 4x16KB @0, B: 4x16KB @65536

  const int tid = threadIdx.x;
  const int l   = tid & 63;
  const int w   = __builtin_amdgcn_readfirstlane(tid >> 6);  // 0..7

  // ---- staging: tile row = c*128 + w*16 + (l>>2)
  const int srow0 = w*16 + (l>>2);
  const int srow1 = 128 + srow0;
  const int schunk = ((l&3) ^ ((l>>3)&3)) * 8;   // pre-swizzled src k-chunk (elems)

  const unsigned short *agp0, *agp1;
  if (PHASE==1){
    const int t0 = (r0 + srow0 < ce) ? tok_of_slot[slotbase + srow0] : 0;
    const int t1 = (r0 + srow1 < ce) ? tok_of_slot[slotbase + srow1] : 0;
    agp0 = A + (size_t)t0*K + schunk;
    agp1 = A + (size_t)t1*K + schunk;
  } else {
    agp0 = A + (size_t)(slotbase + srow0)*K + schunk;
    agp1 = A + (size_t)(slotbase + srow1)*K + schunk;
  }
  const unsigned short* bgp0 = Bt + ((size_t)e*NN + coltile*256 + srow0)*K + schunk;
  const unsigned short* bgp1 = Bt + ((size_t)e*NN + coltile*256 + srow1)*K + schunk;

#define STAGE_A(S, KE) { char* d_ = smem + (S)*16384 + w*1024;          \
    gl16(agp0 + (KE), d_); gl16(agp1 + (KE), d_ + 8192); }
#define STAGE_B(S, KE) { char* d_ = smem + 65536 + (S)*16384 + w*1024;  \
    gl16(bgp0 + (KE), d_); gl16(bgp1 + (KE), d_ + 8192); }

  // ---- fragment read offsets (bytes within a half-slot)
  const int wm = w >> 2, wn = w & 3;        // 2M x 4N wave grid
  const int lm = l & 15;
  const int kg = l >> 4;                    // 0..3 (8-elem chunk within 32-k half)
  const int swz = ((kg ^ ((lm>>1)&3)) * 16);
  int aoff[8], boff[4];
#pragma unroll
  for (int i=0;i<8;i++) aoff[i] = (wm*128 + i*16 + lm)*64 + swz;
#pragma unroll
  for (int i=0;i<4;i++) boff[i] = (wn*64 + i*16 + lm)*64 + swz;

#define LDA(S, MI) (*(const bf16x8*)(smem + (S)*16384 + aoff[MI]))
#define LDB(S, NI) (*(const bf16x8*)(smem + 65536 + (S)*16384 + boff[NI]))

  f32x4 acc[8][4];
#pragma unroll
  for (int i=0;i<8;i++)
#pragma unroll
    for (int j=0;j<4;j++) acc[i][j] = (f32x4){0.f,0.f,0.f,0.f};

#define MFMA_ROW(MI, AF) {                                                      \
    acc[MI][0] = __builtin_amdgcn_mfma_f32_16x16x32_bf16(AF, bfr0, acc[MI][0],0,0,0); \
    acc[MI][1] = __builtin_amdgcn_mfma_f32_16x16x32_bf16(AF, bfr1, acc[MI][1],0,0,0); \
    acc[MI][2] = __builtin_amdgcn_mfma_f32_16x16x32_bf16(AF, bfr2, acc[MI][2],0,0,0); \
    acc[MI][3] = __builtin_amdgcn_mfma_f32_16x16x32_bf16(AF, bfr3, acc[MI][3],0,0,0); }

  bf16x8 bfr0, bfr1, bfr2, bfr3;

#define DO_TILE(T, S0, S1, NS0, NS1) {                                          \
    const int t_ = (T);                                                         \
    const bool pf_ = (t_ + 1 < NT);                                             \
    const int kn_ = (t_ + 1)*64;                                                \
    /* ---- p0: A(s0) m0-3 + B(s0); issue A(t+1,k0) */                          \
    bf16x8 af0 = LDA(S0,0), af1 = LDA(S0,1), af2 = LDA(S0,2), af3 = LDA(S0,3);  \
    bfr0 = LDB(S0,0); bfr1 = LDB(S0,1); bfr2 = LDB(S0,2); bfr3 = LDB(S0,3);     \
    if (pf_) STAGE_A(NS0, kn_);                                                 \
    __builtin_amdgcn_s_barrier();                                               \
    asm volatile("s_waitcnt lgkmcnt(0)" ::: "memory");                          \
    __builtin_amdgcn_s_setprio(1);                                              \
    MFMA_ROW(0, af0); MFMA_ROW(1, af1); MFMA_ROW(2, af2); MFMA_ROW(3, af3);     \
    __builtin_amdgcn_s_setprio(0);                                              \
    __builtin_amdgcn_s_barrier();                                               \
    /* ---- p1: A(s0) m4-7; issue B(t+1,k0); wait for (t,k1) */                 \
    af0 = LDA(S0,4); af1 = LDA(S0,5); af2 = LDA(S0,6); af3 = LDA(S0,7);         \
    if (pf_){ STAGE_B(NS0, kn_);                                                \
              asm volatile("s_waitcnt vmcnt(4)" ::: "memory"); }                \
    else      asm volatile("s_waitcnt vmcnt(0)" ::: "memory");                  \
    __builtin_amdgcn_s_barrier();                                               \
    asm volatile("s_waitcnt lgkmcnt(0)" ::: "memory");                          \
    __builtin_amdgcn_s_setprio(1);                                              \
    MFMA_ROW(4, af0); MFMA_ROW(5, af1); MFMA_ROW(6, af2); MFMA_ROW(7, af3);     \
    __builtin_amdgcn_s_setprio(0);                                              \
    __builtin_amdgcn_s_barrier();                                               \
    /* ---- p2: A(s1) m0-3 + B(s1); issue A(t+1,k1) */                          \
    af0 = LDA(S1,0); af1 = LDA(S1,1); af2 = LDA(S1,2); af3 = LDA(S1,3);         \
    bfr0 = LDB(S1,0); bfr1 = LDB(S1,1); bfr2 = LDB(S1,2); bfr3 = LDB(S1,3);     \
    if (pf_) STAGE_A(NS1, kn_ + 32);                                            \
    __builtin_amdgcn_s_barrier();                                               \
    asm volatile("s_waitcnt lgkmcnt(0)" ::: "memory");                          \
    __builtin_amdgcn_s_setprio(1);                                              \
    MFMA_ROW(0, af0); MFMA_ROW(1, af1); MFMA_ROW(2, af2); MFMA_ROW(3, af3);     \
    __builtin_amdgcn_s_setprio(0);                                              \
    __builtin_amdgcn_s_barrier();                                               \
    /* ---- p3: A(s1) m4-7; issue B(t+1,k1); wait for (t+1,k0) */               \
    af0 = LDA(S1,4); af1 = LDA(S1,5); af2 = LDA(S1,6); af3 = LDA(S1,7);         \
    if (pf_){ STAGE_B(NS1, kn_ + 32);                                           \
              asm volatile("s_waitcnt vmcnt(4)" ::: "memory"); }                \
    __builtin_amdgcn_s_barrier();                                               \
    asm volatile("s_waitcnt lgkmcnt(0)" ::: "memory");                          \
    __builtin_amdgcn_s_setprio(1);                                              \
    MFMA_ROW(4, af0); MFMA_ROW(5, af1); MFMA_ROW(6, af2); MFMA_ROW(7, af3);     \
    __builtin_amdgcn_s_setprio(0);                                              \
    __builtin_amdgcn_s_barrier(); }

  // ---- prologue: stage tile 0 fully (8 loads), wait k0-pair, sync
  STAGE_A(0, 0); STAGE_B(0, 0); STAGE_A(1, 32); STAGE_B(1, 32);
  asm volatile("s_waitcnt vmcnt(4)" ::: "memory");
  __builtin_amdgcn_s_barrier();

  for (int tp = 0; tp < NT; tp += 2){
    DO_TILE(tp,   0, 1, 2, 3);
    DO_TILE(tp+1, 2, 3, 0, 1);
  }

  // ---- epilogue. C/D layout: col = lane&15, row = (lane>>4)*4 + reg
  const float* bp = bias + (size_t)e*NN + coltile*256 + wn*64;
  float bv[4];
#pragma unroll
  for (int ni=0;ni<4;ni++) bv[ni] = bp[ni*16 + lm];

  if (PHASE==1){
    unsigned short* hb = (unsigned short*)Out;
#pragma unroll
    for (int mi=0;mi<8;mi++){
#pragma unroll
      for (int r=0;r<4;r++){
        const int row = wm*128 + mi*16 + kg*4 + r;
        unsigned short* hr = hb + (size_t)(slotbase + row)*NN + coltile*256 + wn*64;
#pragma unroll
        for (int ni=0;ni<4;ni++){
          const float v = acc[mi][ni][r] + bv[ni];
          hr[ni*16 + lm] = f2bf(siluf(v));
        }
      }
    }
  } else {
    float* op = (float*)Out;
#pragma unroll
    for (int mi=0;mi<8;mi++){
#pragma unroll
      for (int r=0;r<4;r++){
        const int row = wm*128 + mi*16 + kg*4 + r;
        if (r0 + row < ce){
          const int tok = tok_of_slot[slotbase + row];
          const float g = gate_value[tok];
          float* orow = op + (size_t)tok*NN + coltile*256 + wn*64;
#pragma unroll
          for (int ni=0;ni<4;ni++)
            orow[ni*16 + lm] = (acc[mi][ni][r] + bv[ni])*g;
        }
      }
    }
  }
#undef STAGE_A
#undef STAGE_B
#undef LDA
#undef LDB
#undef MFMA_ROW
#undef DO_TILE
}

// ---------------------------------------------------------------------------
// Dropped tokens pass through: out[n] = x[n] * gate[n]. One wave per token.
// ---------------------------------------------------------------------------
__global__ __launch_bounds__(256) void passthrough_kernel(
    const float* __restrict__ x, const int* __restrict__ slot_or_neg,
    const float* __restrict__ gate_value, float* __restrict__ out)
{
  const int wave = threadIdx.x >> 6;
  const int lane = threadIdx.x & 63;
  const int n = blockIdx.x*4 + wave;
  if (slot_or_neg[n] >= 0) return;
  const float g = gate_value[n];
#pragma unroll
  for (int k=0;k<4;k++){
    const int d = (k*64 + lane)*4;
    float4 v = *(const float4*)(x + (size_t)n*DDIM + d);
    v.x*=g; v.y*=g; v.z*=g; v.w*=g;
    *(float4*)(out + (size_t)n*DDIM + d) = v;
  }
}

extern "C" void kernel_launch(void* const* d_in, const int* in_sizes, int n_in,
                              void* d_out, int out_size, void* d_ws, size_t ws_size,
                              hipStream_t stream)
{
  const float* x  = (const float*)d_in[0];
  const float* Wr = (const float*)d_in[1];
  const float* br = (const float*)d_in[2];
  const float* W1 = (const float*)d_in[3];
  const float* b1 = (const float*)d_in[4];
  const float* W2 = (const float*)d_in[5];
  const float* b2 = (const float*)d_in[6];
  float* out = (float*)d_out;

  char* ws = (char*)d_ws;
  float*          gate_value  = (float*)(ws + OFF_GATE);
  int*            gate_idx    = (int*)  (ws + OFF_GIDX);
  int*            slot_or_neg = (int*)  (ws + OFF_SLOT);
  int*            tok_of_slot = (int*)  (ws + OFF_TOS);
  int*            cnt         = (int*)  (ws + OFF_CNT);
  int*            pfx         = (int*)  (ws + OFF_PFX);
  float*          partial_imp = (float*)(ws + OFF_PIMP);
  unsigned short* xbf         = (unsigned short*)(ws + OFF_XBF);
  unsigned short* W1t         = (unsigned short*)(ws + OFF_W1T);
  unsigned short* W2t         = (unsigned short*)(ws + OFF_W2T);
  unsigned short* hbf         = (unsigned short*)(ws + OFF_HB);

  // weight transpose+convert (independent of router/scan), single launch
  cvt_w_t<<<dim3(64, 16, 16), 256, 0, stream>>>(W1, W2, W1t, W2t);

  router_kernel<<<NTOK/4, 256, 0, stream>>>(x, Wr, br, gate_value, gate_idx,
                                            partial_imp, xbf);
  scan_kernel<<<1, 256, 0, stream>>>(gate_idx, partial_imp, slot_or_neg, tok_of_slot,
                                     cnt, pfx, out + (size_t)NTOK*DDIM);

  ffn_mfma<1><<<dim3((ECAP/256)*(HDIM/256)), 512, 0, stream>>>(
      xbf, W1t, b1, tok_of_slot, cnt, pfx, gate_value, (void*)hbf);
  ffn_mfma<2><<<dim3((ECAP/256)*(DDIM/256)), 512, 0, stream>>>(
      hbf, W2t, b2, tok_of_slot, cnt, pfx, gate_value, (void*)out);

  passthrough_kernel<<<NTOK/4, 256, 0, stream>>>(x, slot_or_neg, gate_value, out);
}